// Round 16
// baseline (86.758 us; speedup 1.0000x reference)
//
#include <hip/hip_runtime.h>

#define NB 16
#define NL 1024
#define ND 64
#define NW 20
#define CH 16                   // l's per block (rolling), FULLY unrolled
#define THR 0.3f

typedef float f32x4 __attribute__((ext_vector_type(4)));

static __device__ __forceinline__ f32x4 splat4(float v) {
    f32x4 r = {v, v, v, v};
    return r;
}

// Rolling-window, 256 threads per (b, 16-l chunk). Strided row ownership
// (R12): store instruction i covers 1KB contiguous per wave.
// R16: attack ISSUE COUNT (R14 ablation: compute-bound at 97% VALUBusy;
// R15's raw sqrt/rcp gave only -6us => remaining bloat is addressing +
// scalar-float issue slots):
//  (a) FULL unroll of the l-loop: all LDS reads become imm-offset, store
//      rows become imm-offset, no per-step address VALU.
//  (b) f32x4 vector arithmetic for Gram/col-state/epilogue -> v_pk_*_f32
//      dual-FP32 ops halve issue slots for the fma/mul/max bulk.
// EPILOGUE eps EXACT (x19-rescale): den = sdu*seu + 19e-8 == 19*(sd*se+1e-8);
// corr = 19cov/19den (R8's absmax-0.7 bug was eps REMOVAL, not rescaling).
// RULES: no runtime indexing into register arrays (R5: scratch demotion, 6x);
// no __launch_bounds__ occupancy hints (R3/R4: forced spill).
__global__ void dyn_corr_kernel(const float* __restrict__ x,
                                float* __restrict__ out)
{
    const int blk = blockIdx.x;            // 0..1023
    const int b   = blk >> 6;              // 64 chunks per batch
    const int l0  = (blk & 63) * CH;
    const int t   = threadIdx.x;           // 0..255

    const int NROW = NW - 1 + CH;          // 35 staged rows
    __shared__ float win[NW - 1 + CH][ND]; // 8960 B, raw (uncentered)

    const float* xb = x + ((size_t)b * NL) * ND;

    // --- stage 35 rows (zeros for l<0), f32x4, coalesced ---
    #pragma unroll
    for (int i = 0; i < 3; ++i) {
        int s = t + i * 256;               // valid < 560
        if (s < NROW * 16) {
            int w    = s >> 4;
            int c4   = (s & 15) << 2;
            int lsrc = l0 - (NW - 1) + w;
            f32x4 v = {0.f, 0.f, 0.f, 0.f};
            if (lsrc >= 0) v = *(const f32x4*)&xb[(size_t)lsrc * ND + c4];
            *(f32x4*)&win[w][c4] = v;
        }
    }
    __syncthreads();                       // win read-only from here on

    const int q  = t >> 6;                 // wave 0..3 -> rows 16q..16q+15
    const int g  = (t >> 4) & 3;           // row-group within wave
    const int tc = t & 15;                 // col group
    const int r0 = (q << 4) + g;           // row(i) = r0 + 4*i
    const int e0 = tc << 2;                // cols e0..e0+3

    f32x4 acc0 = {}, acc1 = {}, acc2 = {}, acc3 = {};  // Gram rows
    float rs0 = 0.f, rs1 = 0.f, rs2 = 0.f, rs3 = 0.f;  // row sums
    float rq0 = 0.f, rq1 = 0.f, rq2 = 0.f, rq3 = 0.f;  // row sumsq
    f32x4 csv = {}, cqv = {};                          // col sum / sumsq

    // --- init: full first window, LDS rows 0..19 ---
    #pragma unroll
    for (int w = 0; w < NW; ++w) {
        float a0 = win[w][r0];
        float a1 = win[w][r0 + 4];
        float a2 = win[w][r0 + 8];
        float a3 = win[w][r0 + 12];
        f32x4 bv = *(const f32x4*)&win[w][e0];
        csv += bv;
        cqv += bv * bv;
        rs0 += a0; rq0 += a0 * a0; acc0 += splat4(a0) * bv;
        rs1 += a1; rq1 += a1 * a1; acc1 += splat4(a1) * bv;
        rs2 += a2; rq2 += a2 * a2; acc2 += splat4(a2) * bv;
        rs3 += a3; rq3 += a3 * a3; acc3 += splat4(a3) * bv;
    }

    const float invW  = 1.0f / NW;
    const f32x4 vEPS  = {19e-8f, 19e-8f, 19e-8f, 19e-8f};
    const f32x4 vTHR  = {THR, THR, THR, THR};
    const f32x4 vZERO = {0.f, 0.f, 0.f, 0.f};
    float* obase = out + ((size_t)b * NL + l0) * (ND * ND);

    #pragma unroll
    for (int s = 0; s < CH; ++s) {
        // --- epilogue for l = l0 + s (x19-rescaled, eps semantics exact) ---
        f32x4 mcv = csv * invW;
        f32x4 qcv = cqv - csv * mcv;       // 19*var (cols)
        f32x4 seuv;
        seuv.x = __builtin_amdgcn_sqrtf(qcv.x);
        seuv.y = __builtin_amdgcn_sqrtf(qcv.y);
        seuv.z = __builtin_amdgcn_sqrtf(qcv.z);
        seuv.w = __builtin_amdgcn_sqrtf(qcv.w);
        float sdu0 = __builtin_amdgcn_sqrtf(rq0 - rs0 * invW * rs0);
        float sdu1 = __builtin_amdgcn_sqrtf(rq1 - rs1 * invW * rs1);
        float sdu2 = __builtin_amdgcn_sqrtf(rq2 - rs2 * invW * rs2);
        float sdu3 = __builtin_amdgcn_sqrtf(rq3 - rs3 * invW * rs3);

        float* ob = obase + (size_t)s * (ND * ND);
        {
            f32x4 cv  = acc0 - splat4(rs0) * mcv;
            f32x4 den = splat4(sdu0) * seuv + vEPS;
            f32x4 rv;
            rv.x = __builtin_amdgcn_rcpf(den.x);
            rv.y = __builtin_amdgcn_rcpf(den.y);
            rv.z = __builtin_amdgcn_rcpf(den.z);
            rv.w = __builtin_amdgcn_rcpf(den.w);
            f32x4 o = __builtin_elementwise_max(
                __builtin_elementwise_abs(cv * rv) - vTHR, vZERO);
            __builtin_nontemporal_store(o, (f32x4*)&ob[(r0 + 0) * ND + e0]);
        }
        {
            f32x4 cv  = acc1 - splat4(rs1) * mcv;
            f32x4 den = splat4(sdu1) * seuv + vEPS;
            f32x4 rv;
            rv.x = __builtin_amdgcn_rcpf(den.x);
            rv.y = __builtin_amdgcn_rcpf(den.y);
            rv.z = __builtin_amdgcn_rcpf(den.z);
            rv.w = __builtin_amdgcn_rcpf(den.w);
            f32x4 o = __builtin_elementwise_max(
                __builtin_elementwise_abs(cv * rv) - vTHR, vZERO);
            __builtin_nontemporal_store(o, (f32x4*)&ob[(r0 + 4) * ND + e0]);
        }
        {
            f32x4 cv  = acc2 - splat4(rs2) * mcv;
            f32x4 den = splat4(sdu2) * seuv + vEPS;
            f32x4 rv;
            rv.x = __builtin_amdgcn_rcpf(den.x);
            rv.y = __builtin_amdgcn_rcpf(den.y);
            rv.z = __builtin_amdgcn_rcpf(den.z);
            rv.w = __builtin_amdgcn_rcpf(den.w);
            f32x4 o = __builtin_elementwise_max(
                __builtin_elementwise_abs(cv * rv) - vTHR, vZERO);
            __builtin_nontemporal_store(o, (f32x4*)&ob[(r0 + 8) * ND + e0]);
        }
        {
            f32x4 cv  = acc3 - splat4(rs3) * mcv;
            f32x4 den = splat4(sdu3) * seuv + vEPS;
            f32x4 rv;
            rv.x = __builtin_amdgcn_rcpf(den.x);
            rv.y = __builtin_amdgcn_rcpf(den.y);
            rv.z = __builtin_amdgcn_rcpf(den.z);
            rv.w = __builtin_amdgcn_rcpf(den.w);
            f32x4 o = __builtin_elementwise_max(
                __builtin_elementwise_abs(cv * rv) - vTHR, vZERO);
            __builtin_nontemporal_store(o, (f32x4*)&ob[(r0 + 12) * ND + e0]);
        }

        // --- rolling update l -> l+1 (imm-offset LDS, compile-time s) ---
        if (s < CH - 1) {
            float an0 = win[s + NW][r0];
            float an1 = win[s + NW][r0 + 4];
            float an2 = win[s + NW][r0 + 8];
            float an3 = win[s + NW][r0 + 12];
            float ao0 = win[s][r0];
            float ao1 = win[s][r0 + 4];
            float ao2 = win[s][r0 + 8];
            float ao3 = win[s][r0 + 12];
            f32x4 nb = *(const f32x4*)&win[s + NW][e0];
            f32x4 ov = *(const f32x4*)&win[s][e0];
            csv += nb - ov;
            cqv += nb * nb - ov * ov;
            rs0 += an0 - ao0; rq0 += an0 * an0 - ao0 * ao0;
            rs1 += an1 - ao1; rq1 += an1 * an1 - ao1 * ao1;
            rs2 += an2 - ao2; rq2 += an2 * an2 - ao2 * ao2;
            rs3 += an3 - ao3; rq3 += an3 * an3 - ao3 * ao3;
            acc0 += splat4(an0) * nb - splat4(ao0) * ov;
            acc1 += splat4(an1) * nb - splat4(ao1) * ov;
            acc2 += splat4(an2) * nb - splat4(ao2) * ov;
            acc3 += splat4(an3) * nb - splat4(ao3) * ov;
        }
    }
}

extern "C" void kernel_launch(void* const* d_in, const int* in_sizes, int n_in,
                              void* d_out, int out_size, void* d_ws, size_t ws_size,
                              hipStream_t stream) {
    const float* x = (const float*)d_in[0];
    float* out = (float*)d_out;
    dim3 grid(NB * (NL / CH));
    dim3 block(256);
    hipLaunchKernelGGL(dyn_corr_kernel, grid, block, 0, stream, x, out);
}